// Round 3
// baseline (1536.861 us; speedup 1.0000x reference)
//
#include <hip/hip_runtime.h>

#define PN 10000
#define UN 8000
#define BN 4096
#define NGE 320000
#define NDE 320000
#define NUE 400000
#define NPUE 400000
#define INV_T 5.0f

// ---------------- single gate: out = pe * sigmoid(pe @ W + b)
__global__ void gate_kernel(const float* __restrict__ poi,
                            const float* __restrict__ wg, const float* __restrict__ bg,
                            float* __restrict__ og) {
    __shared__ float W[64][64];
    __shared__ float Bv[64];
    __shared__ float pe[4][64];
    int tid = threadIdx.x;
    for (int t = tid; t < 4096; t += 256) {
        W[t >> 6][t & 63] = wg[t];
    }
    if (tid < 64) Bv[tid] = bg[tid];
    int r0 = blockIdx.x * 4;
    {
        int r = tid >> 6, k = tid & 63;
        pe[r][k] = poi[(r0 + r) * 64 + k];
    }
    __syncthreads();
    int r = tid >> 6, j = tid & 63;
    float acc = Bv[j];
#pragma unroll
    for (int k = 0; k < 64; k++) acc += pe[r][k] * W[k][j];
    float sg = 1.0f / (1.0f + __expf(-acc));
    og[(r0 + r) * 64 + j] = pe[r][j] * sg;
}

// ---------------- SpMM: y[rows[e],:] += vals[e] * x[cols[e],:]  (atomic, wave per edge)
__global__ void spmm_kernel(const int* __restrict__ rows, const int* __restrict__ cols,
                            const float* __restrict__ vals, const float* __restrict__ x,
                            float* __restrict__ y, int nnz) {
    int lane = threadIdx.x & 63;
    int wave = (blockIdx.x * blockDim.x + threadIdx.x) >> 6;
    int nw = (gridDim.x * blockDim.x) >> 6;
    for (int e = wave; e < nnz; e += nw) {
        int r = rows[e] * 64 + lane;
        int c = cols[e] * 64 + lane;
        float v = vals[e];
        atomicAdd(&y[r], v * x[c]);
    }
}

// three SpMMs sharing one index set (up matrix)
__global__ void spmm3_kernel(const int* __restrict__ rows, const int* __restrict__ cols,
                             const float* __restrict__ vals,
                             const float* __restrict__ x0, const float* __restrict__ x1,
                             const float* __restrict__ x2,
                             float* __restrict__ y0, float* __restrict__ y1,
                             float* __restrict__ y2, int nnz) {
    int lane = threadIdx.x & 63;
    int wave = (blockIdx.x * blockDim.x + threadIdx.x) >> 6;
    int nw = (gridDim.x * blockDim.x) >> 6;
    for (int e = wave; e < nnz; e += nw) {
        int r = rows[e] * 64 + lane;
        int c = cols[e] * 64 + lane;
        float v = vals[e];
        atomicAdd(&y0[r], v * x0[c]);
        atomicAdd(&y1[r], v * x1[c]);
        atomicAdd(&y2[r], v * x2[c]);
    }
}

// ---------------- elementwise helpers
__global__ void add_in_kernel(float4* __restrict__ dst, const float4* __restrict__ a, int n4) {
    int i = blockIdx.x * blockDim.x + threadIdx.x;
    if (i < n4) {
        float4 d = dst[i], s = a[i];
        d.x += s.x; d.y += s.y; d.z += s.z; d.w += s.w;
        dst[i] = d;
    }
}

__global__ void avg3_kernel(float4* __restrict__ dst, const float4* __restrict__ a,
                            const float4* __restrict__ b, int n4) {
    const float t = 1.0f / 3.0f;
    int i = blockIdx.x * blockDim.x + threadIdx.x;
    if (i < n4) {
        float4 d = dst[i], x = a[i], y = b[i];
        d.x = (d.x + x.x + y.x) * t; d.y = (d.y + x.y + y.y) * t;
        d.z = (d.z + x.z + y.z) * t; d.w = (d.w + x.w + y.w) * t;
        dst[i] = d;
    }
}

// ---------------- row l2-normalize (wave per row, in-place safe)
__global__ void l2norm_kernel(const float* __restrict__ x, float* __restrict__ y, int nrows) {
    int lane = threadIdx.x & 63;
    int row = (blockIdx.x * blockDim.x + threadIdx.x) >> 6;
    if (row >= nrows) return;
    float v = x[row * 64 + lane];
    float s = v * v;
#pragma unroll
    for (int off = 32; off > 0; off >>= 1) s += __shfl_xor(s, off, 64);
    float d = fmaxf(sqrtf(s), 1e-12f);
    y[row * 64 + lane] = v / d;
}

// ---------------- fused InfoNCE statistics: rowsum/colsum of exp(A·B^T/T), diag
__global__ __launch_bounds__(256, 4) void infonce_kernel(
        const float* __restrict__ A, const float* __restrict__ B,
        float* __restrict__ rowsum, float* __restrict__ colsum, float* __restrict__ pos) {
    __shared__ float4 Bs[128 * 16];
    int tid = threadIdx.x;
    int i = blockIdx.x * 256 + tid;
    int j0 = blockIdx.y * 128;
    bool iv = (i < PN);
    float a[64];
    {
        const float4* A4 = (const float4*)(A + (size_t)i * 64);
#pragma unroll
        for (int k4 = 0; k4 < 16; k4++) {
            float4 t = iv ? A4[k4] : make_float4(0.f, 0.f, 0.f, 0.f);
            a[k4 * 4 + 0] = t.x; a[k4 * 4 + 1] = t.y; a[k4 * 4 + 2] = t.z; a[k4 * 4 + 3] = t.w;
        }
    }
    for (int t = tid; t < 2048; t += 256) {
        int row = t >> 4, kk = t & 15;
        int j = j0 + row;
        Bs[t] = (j < PN) ? ((const float4*)(B + (size_t)j * 64))[kk] : make_float4(0.f, 0.f, 0.f, 0.f);
    }
    __syncthreads();
    int lane = tid & 63;
    float rsum = 0.0f;
    int jmax = min(128, PN - j0);
    for (int c = 0; c < jmax; c++) {
        float s0 = 0.f, s1 = 0.f, s2 = 0.f, s3 = 0.f;
#pragma unroll
        for (int kk = 0; kk < 16; kk++) {
            float4 b4 = Bs[c * 16 + kk];
            s0 += a[kk * 4 + 0] * b4.x;
            s1 += a[kk * 4 + 1] * b4.y;
            s2 += a[kk * 4 + 2] * b4.z;
            s3 += a[kk * 4 + 3] * b4.w;
        }
        float s = (s0 + s1) + (s2 + s3);
        float e = iv ? __expf(s * INV_T) : 0.0f;
        rsum += e;
        int jc = j0 + c;
        if (iv && jc == i) pos[i] = e;
        float wsum = e;
#pragma unroll
        for (int off = 32; off > 0; off >>= 1) wsum += __shfl_xor(wsum, off, 64);
        if (lane == 0) atomicAdd(&colsum[jc], wsum);
    }
    if (iv) atomicAdd(&rowsum[i], rsum);
}

// ---------------- hg_users: msg_emb + ue + msg_emb*ue; SAFE if hg aliases mp
__global__ void fuse_users_kernel(const float* __restrict__ mg, const float* __restrict__ ms,
                                  const float* __restrict__ mp, const float* __restrict__ fw,
                                  const float* __restrict__ fb, const float* __restrict__ ue,
                                  float* __restrict__ hg) {
    __shared__ float G[4][64], S[4][64], Pm[4][64];
    int tid = threadIdx.x;
    int u0 = blockIdx.x * 4;
    {
        int r = tid >> 6, k = tid & 63;
        int o = (u0 + r) * 64 + k;
        G[r][k] = mg[o]; S[r][k] = ms[o]; Pm[r][k] = mp[o];
    }
    __syncthreads();
    int r = tid >> 6, j = tid & 63;
    float acc = fb[j];
    for (int k = 0; k < 64; k++) {
        float g = G[r][k], s = S[r][k], p = Pm[r][k];
        float gs = g * s, gp = g * p, sp = s * p, gsp = gs * p;
        acc += g   * fw[(0 * 64 + k) * 64 + j];
        acc += s   * fw[(1 * 64 + k) * 64 + j];
        acc += p   * fw[(2 * 64 + k) * 64 + j];
        acc += gs  * fw[(3 * 64 + k) * 64 + j];
        acc += gp  * fw[(4 * 64 + k) * 64 + j];
        acc += sp  * fw[(5 * 64 + k) * 64 + j];
        acc += gsp * fw[(6 * 64 + k) * 64 + j];
    }
    int o = (u0 + r) * 64 + j;
    float u = ue[o];
    hg[o] = acc + u + acc * u;
}

// ---------------- fusion_pois = l2norm(hg_pois) + ng + ns -> f32 fp (ws) + out
__global__ void fusion_out_kernel(const float* __restrict__ hgp, const float* __restrict__ ng,
                                  const float* __restrict__ ns, float* __restrict__ fp,
                                  float* __restrict__ outp) {
    int lane = threadIdx.x & 63;
    int row = (blockIdx.x * blockDim.x + threadIdx.x) >> 6;
    if (row >= PN) return;
    int o = row * 64 + lane;
    float v = hgp[o];
    float s = v * v;
#pragma unroll
    for (int off = 32; off > 0; off >>= 1) s += __shfl_xor(s, off, 64);
    float d = fmaxf(sqrtf(s), 1e-12f);
    float f = v / d + ng[o] + ns[o];
    fp[o] = f;
    outp[o] = f;
}

// ---------------- batch_users = l2norm(users_struct[user_idx]) -> out
__global__ void batch_out_kernel(const float* __restrict__ us, const int* __restrict__ idx,
                                 float* __restrict__ outp) {
    int lane = threadIdx.x & 63;
    int b = (blockIdx.x * blockDim.x + threadIdx.x) >> 6;
    if (b >= BN) return;
    int r = idx[b];
    float v = us[r * 64 + lane];
    float s = v * v;
#pragma unroll
    for (int off = 32; off > 0; off >>= 1) s += __shfl_xor(s, off, 64);
    float d = fmaxf(sqrtf(s), 1e-12f);
    outp[b * 64 + lane] = v / d;
}

// ---------------- loss scalar
__global__ void loss_kernel(const float* __restrict__ pos, const float* __restrict__ n1,
                            const float* __restrict__ n2, float* __restrict__ outp) {
    __shared__ float red[256];
    int tid = threadIdx.x;
    float acc = 0.0f;
    for (int i = tid; i < PN; i += 256) {
        float p = pos[i];
        acc += -logf(p / (n1[i] + 1e-8f) + 1e-8f);
        acc += -logf(p / (n2[i] + 1e-8f) + 1e-8f);
    }
    red[tid] = acc;
    __syncthreads();
    for (int s = 128; s > 0; s >>= 1) {
        if (tid < s) red[tid] += red[tid + s];
        __syncthreads();
    }
    if (tid == 0) outp[0] = 0.5f * red[0] / (float)PN;
}

extern "C" void kernel_launch(void* const* d_in, const int* in_sizes, int n_in,
                              void* d_out, int out_size, void* d_ws, size_t ws_size,
                              hipStream_t stream) {
    (void)in_sizes; (void)n_in; (void)out_size; (void)ws_size;
    const float* poi  = (const float*)d_in[0];
    const float* uemb = (const float*)d_in[1];
    const float* wgg  = (const float*)d_in[2];
    const float* bgg  = (const float*)d_in[3];
    const float* wgs  = (const float*)d_in[4];
    const float* bgs  = (const float*)d_in[5];
    const float* wgc  = (const float*)d_in[6];
    const float* bgc  = (const float*)d_in[7];
    const float* fw   = (const float*)d_in[8];
    const float* fb   = (const float*)d_in[9];
    const float* geo_vals = (const float*)d_in[10];
    const float* src_vals = (const float*)d_in[11];
    const float* tar_vals = (const float*)d_in[12];
    const float* up_vals  = (const float*)d_in[13];
    const float* pu_vals  = (const float*)d_in[14];
    const int* geo_rows = (const int*)d_in[15];
    const int* geo_cols = (const int*)d_in[16];
    const int* src_rows = (const int*)d_in[17];
    const int* src_cols = (const int*)d_in[18];
    const int* tar_rows = (const int*)d_in[19];
    const int* tar_cols = (const int*)d_in[20];
    const int* up_rows  = (const int*)d_in[21];
    const int* up_cols  = (const int*)d_in[22];
    const int* pu_rows  = (const int*)d_in[23];
    const int* pu_cols  = (const int*)d_in[24];
    const int* user_idx = (const int*)d_in[25];

    const int PD = PN * 64, UD = UN * 64;
    const size_t PDB = (size_t)PD * sizeof(float);
    const size_t UDB = (size_t)UD * sizeof(float);

    // workspace layout: 3*PN + UD + 5*PD floats ≈ 15 MB
    float* w = (float*)d_ws;
    float* rowsum = w;               // PN
    float* colsum = rowsum + PN;     // PN
    float* pos    = colsum + PN;     // PN
    float* U0     = pos + PN;        // UD (m_poi / hg_users alias)
    float* P0     = U0 + UD;         // PD pools
    float* P1     = P0 + PD;
    float* P2     = P1 + PD;
    float* P3     = P2 + PD;
    float* P4     = P3 + PD;

    float* out_bu = (float*)d_out;               // 4096*64
    float* out_fp = out_bu + (size_t)BN * 64;    // 10000*64
    float* out_loss = out_fp + (size_t)PN * 64;  // 1

    const int n4 = PD / 4;          // 160000
    const int EB = 625;             // n4/256
    const int SG = 4096;            // spmm grid
    const int RB = PN / 4;          // 2500 row-blocks

    hipMemsetAsync(rowsum, 0, 3 * (size_t)PN * sizeof(float), stream);

    // ---- geo chain: ng = l2norm((g + x1 + x2)/3), x1=Ag+g, x2=Ax1+x1
    gate_kernel<<<RB, 256, 0, stream>>>(poi, wgg, bgg, P0);            // geo_g
    hipMemsetAsync(P1, 0, PDB, stream);
    spmm_kernel<<<SG, 256, 0, stream>>>(geo_rows, geo_cols, geo_vals, P0, P1, NGE);
    add_in_kernel<<<EB, 256, 0, stream>>>((float4*)P1, (const float4*)P0, n4);   // x1
    hipMemsetAsync(P2, 0, PDB, stream);
    spmm_kernel<<<SG, 256, 0, stream>>>(geo_rows, geo_cols, geo_vals, P1, P2, NGE);
    add_in_kernel<<<EB, 256, 0, stream>>>((float4*)P2, (const float4*)P1, n4);   // x2
    avg3_kernel<<<EB, 256, 0, stream>>>((float4*)P2, (const float4*)P0, (const float4*)P1, n4);
    l2norm_kernel<<<RB, 256, 0, stream>>>(P2, P2, PN);                  // ng = P2

    // ---- seq chain: x_{k+1} = S (T x_k) + x_k
    gate_kernel<<<RB, 256, 0, stream>>>(poi, wgs, bgs, P0);            // seq_g
    hipMemsetAsync(P1, 0, PDB, stream);
    spmm_kernel<<<SG, 256, 0, stream>>>(tar_rows, tar_cols, tar_vals, P0, P1, NDE);  // m1
    hipMemsetAsync(P3, 0, PDB, stream);
    spmm_kernel<<<SG, 256, 0, stream>>>(src_rows, src_cols, src_vals, P1, P3, NDE);
    add_in_kernel<<<EB, 256, 0, stream>>>((float4*)P3, (const float4*)P0, n4);   // x1
    hipMemsetAsync(P1, 0, PDB, stream);
    spmm_kernel<<<SG, 256, 0, stream>>>(tar_rows, tar_cols, tar_vals, P3, P1, NDE);  // m2
    hipMemsetAsync(P4, 0, PDB, stream);
    spmm_kernel<<<SG, 256, 0, stream>>>(src_rows, src_cols, src_vals, P1, P4, NDE);
    add_in_kernel<<<EB, 256, 0, stream>>>((float4*)P4, (const float4*)P3, n4);   // x2
    avg3_kernel<<<EB, 256, 0, stream>>>((float4*)P4, (const float4*)P0, (const float4*)P3, n4);
    l2norm_kernel<<<RB, 256, 0, stream>>>(P4, P4, PN);                  // ns = P4

    // ---- InfoNCE statistics (single fused pass over ng·ns^T)
    dim3 ig(40, 79);
    infonce_kernel<<<ig, 256, 0, stream>>>(P2, P4, rowsum, colsum, pos);

    // ---- multi-view (loop-invariant fold): hg_pois = col_g + PU @ hg_users
    gate_kernel<<<RB, 256, 0, stream>>>(poi, wgc, bgc, P0);            // col_g
    hipMemsetAsync(P1, 0, UDB, stream);
    hipMemsetAsync(P3, 0, UDB, stream);
    hipMemsetAsync(U0, 0, UDB, stream);
    spmm3_kernel<<<SG, 256, 0, stream>>>(up_rows, up_cols, up_vals, P2, P4, P0,
                                         P1, P3, U0, NUE);             // m_geo,m_seq,m_poi
    fuse_users_kernel<<<UN / 4, 256, 0, stream>>>(P1, P3, U0, fw, fb, uemb, U0); // hg_u=U0
    hipMemsetAsync(P1, 0, PDB, stream);
    spmm_kernel<<<SG, 256, 0, stream>>>(pu_rows, pu_cols, pu_vals, U0, P1, NPUE);
    add_in_kernel<<<EB, 256, 0, stream>>>((float4*)P1, (const float4*)P0, n4);   // hg_pois

    // ---- outputs
    fusion_out_kernel<<<RB, 256, 0, stream>>>(P1, P2, P4, P3, out_fp);  // fuse f32 = P3
    hipMemsetAsync(P0, 0, UDB, stream);
    spmm_kernel<<<SG, 256, 0, stream>>>(up_rows, up_cols, up_vals, P3, P0, NUE); // ustr
    batch_out_kernel<<<BN / 4, 256, 0, stream>>>(P0, user_idx, out_bu);
    loss_kernel<<<1, 256, 0, stream>>>(pos, rowsum, colsum, out_loss);
}

// Round 5
// 768.752 us; speedup vs baseline: 1.9992x; 1.9992x over previous
//
#include <hip/hip_runtime.h>

#define PN 10000
#define UN 8000
#define BN 4096
#define NGE 320000
#define NDE 320000
#define NUE 400000
#define NPUE 400000
#define INV_T 5.0f

typedef __attribute__((ext_vector_type(8))) short short8;
typedef __attribute__((ext_vector_type(4))) float f32x4;
typedef unsigned short u16;
typedef unsigned int u32;

__device__ __forceinline__ u16 f2bf(float x) {
    u32 u = __float_as_uint(x);
    return (u16)((u + 0x7FFFu + ((u >> 16) & 1u)) >> 16);
}

// ---------------- gate: out = pe * sigmoid(pe @ W + b)
__global__ void gate_kernel(const float* __restrict__ poi,
                            const float* __restrict__ wg, const float* __restrict__ bg,
                            float* __restrict__ og) {
    __shared__ float W[64][64];
    __shared__ float Bv[64];
    __shared__ float pe[4][64];
    int tid = threadIdx.x;
    for (int t = tid; t < 4096; t += 256) W[t >> 6][t & 63] = wg[t];
    if (tid < 64) Bv[tid] = bg[tid];
    int r0 = blockIdx.x * 4;
    {
        int r = tid >> 6, k = tid & 63;
        pe[r][k] = poi[(r0 + r) * 64 + k];
    }
    __syncthreads();
    int r = tid >> 6, j = tid & 63;
    float acc = Bv[j];
#pragma unroll
    for (int k = 0; k < 64; k++) acc += pe[r][k] * W[k][j];
    float sg = 1.0f / (1.0f + __expf(-acc));
    og[(r0 + r) * 64 + j] = pe[r][j] * sg;
}

// ================= CSR build =================
__global__ void hist_kernel(const int* __restrict__ rows, int* __restrict__ cnt, int nnz) {
    int e = blockIdx.x * blockDim.x + threadIdx.x;
    if (e < nnz) atomicAdd(&cnt[rows[e]], 1);
}

__global__ void scan_kernel(int* __restrict__ cnt, int* __restrict__ rp, int n, int nnz) {
    __shared__ int part[1024];
    int tid = threadIdx.x;
    int chunk = (n + 1023) >> 10;
    int base = tid * chunk;
    int s = 0;
    for (int k = 0; k < chunk; k++) {
        int i = base + k;
        if (i < n) s += cnt[i];
    }
    part[tid] = s;
    __syncthreads();
    for (int off = 1; off < 1024; off <<= 1) {
        int v = (tid >= off) ? part[tid - off] : 0;
        __syncthreads();
        part[tid] += v;
        __syncthreads();
    }
    int pre = (tid > 0) ? part[tid - 1] : 0;
    for (int k = 0; k < chunk; k++) {
        int i = base + k;
        if (i < n) {
            int c = cnt[i];
            rp[i] = pre;
            cnt[i] = pre;   // becomes cursor
            pre += c;
        }
    }
    if (tid == 0) rp[n] = nnz;
}

__global__ void scatter_kernel(const int* __restrict__ rows, const int* __restrict__ cols,
                               const float* __restrict__ vals, int* __restrict__ cur,
                               int2* __restrict__ ent, int nnz) {
    int e = blockIdx.x * blockDim.x + threadIdx.x;
    if (e < nnz) {
        int p = atomicAdd(&cur[rows[e]], 1);
        ent[p] = make_int2(cols[e], __float_as_int(vals[e]));
    }
}

// ================= CSR SpMM: wave per row, register accumulate =================
__global__ void spmm_csr_kernel(const int* __restrict__ rp, const int2* __restrict__ ent,
                                const float* __restrict__ x, const float* __restrict__ add,
                                float* __restrict__ y, int nrows) {
    int lane = threadIdx.x & 63;
    int row = (blockIdx.x * blockDim.x + threadIdx.x) >> 6;
    if (row >= nrows) return;
    int s = rp[row], e = rp[row + 1];
    float acc = add ? add[row * 64 + lane] : 0.0f;
    int p = s;
    for (; p + 4 <= e; p += 4) {
        int2 c0 = ent[p], c1 = ent[p + 1], c2 = ent[p + 2], c3 = ent[p + 3];
        float v0 = x[(size_t)c0.x * 64 + lane];
        float v1 = x[(size_t)c1.x * 64 + lane];
        float v2 = x[(size_t)c2.x * 64 + lane];
        float v3 = x[(size_t)c3.x * 64 + lane];
        acc = fmaf(__int_as_float(c0.y), v0, acc);
        acc = fmaf(__int_as_float(c1.y), v1, acc);
        acc = fmaf(__int_as_float(c2.y), v2, acc);
        acc = fmaf(__int_as_float(c3.y), v3, acc);
    }
    for (; p < e; ++p) {
        int2 c = ent[p];
        acc = fmaf(__int_as_float(c.y), x[(size_t)c.x * 64 + lane], acc);
    }
    y[row * 64 + lane] = acc;
}

__global__ void spmm3_csr_kernel(const int* __restrict__ rp, const int2* __restrict__ ent,
                                 const float* __restrict__ x0, const float* __restrict__ x1,
                                 const float* __restrict__ x2,
                                 float* __restrict__ y0, float* __restrict__ y1,
                                 float* __restrict__ y2, int nrows) {
    int lane = threadIdx.x & 63;
    int row = (blockIdx.x * blockDim.x + threadIdx.x) >> 6;
    if (row >= nrows) return;
    int s = rp[row], e = rp[row + 1];
    float a0 = 0.f, a1 = 0.f, a2 = 0.f;
    for (int p = s; p < e; ++p) {
        int2 c = ent[p];
        float v = __int_as_float(c.y);
        size_t o = (size_t)c.x * 64 + lane;
        a0 = fmaf(v, x0[o], a0);
        a1 = fmaf(v, x1[o], a1);
        a2 = fmaf(v, x2[o], a2);
    }
    size_t o = (size_t)row * 64 + lane;
    y0[o] = a0; y1[o] = a1; y2[o] = a2;
}

// ================= atomic-SpMM fallback path =================
__global__ void spmm_kernel(const int* __restrict__ rows, const int* __restrict__ cols,
                            const float* __restrict__ vals, const float* __restrict__ x,
                            float* __restrict__ y, int nnz) {
    int lane = threadIdx.x & 63;
    int wave = (blockIdx.x * blockDim.x + threadIdx.x) >> 6;
    int nw = (gridDim.x * blockDim.x) >> 6;
    for (int e = wave; e < nnz; e += nw) {
        atomicAdd(&y[rows[e] * 64 + lane], vals[e] * x[cols[e] * 64 + lane]);
    }
}

__global__ void spmm3_kernel(const int* __restrict__ rows, const int* __restrict__ cols,
                             const float* __restrict__ vals,
                             const float* __restrict__ x0, const float* __restrict__ x1,
                             const float* __restrict__ x2,
                             float* __restrict__ y0, float* __restrict__ y1,
                             float* __restrict__ y2, int nnz) {
    int lane = threadIdx.x & 63;
    int wave = (blockIdx.x * blockDim.x + threadIdx.x) >> 6;
    int nw = (gridDim.x * blockDim.x) >> 6;
    for (int e = wave; e < nnz; e += nw) {
        int r = rows[e] * 64 + lane;
        int c = cols[e] * 64 + lane;
        float v = vals[e];
        atomicAdd(&y0[r], v * x0[c]);
        atomicAdd(&y1[r], v * x1[c]);
        atomicAdd(&y2[r], v * x2[c]);
    }
}

__global__ void add_in_kernel(float4* __restrict__ dst, const float4* __restrict__ a, int n4) {
    int i = blockIdx.x * blockDim.x + threadIdx.x;
    if (i < n4) {
        float4 d = dst[i], s = a[i];
        d.x += s.x; d.y += s.y; d.z += s.z; d.w += s.w;
        dst[i] = d;
    }
}

// ---------------- avg-of-3 + l2norm fused (wave per row); optional bf16 copy
__global__ void avg_norm_kernel(const float* __restrict__ a, const float* __restrict__ b,
                                const float* __restrict__ c, float* __restrict__ yf,
                                u16* __restrict__ yb, int nrows) {
    int lane = threadIdx.x & 63;
    int row = (blockIdx.x * blockDim.x + threadIdx.x) >> 6;
    if (row >= nrows) return;
    int o = row * 64 + lane;
    float v = (a[o] + b[o] + c[o]) * (1.0f / 3.0f);
    float s = v * v;
#pragma unroll
    for (int off = 32; off > 0; off >>= 1) s += __shfl_xor(s, off, 64);
    float d = fmaxf(sqrtf(s), 1e-12f);
    float r = v / d;
    yf[o] = r;
    if (yb) yb[o] = f2bf(r);
}

// ================= MFMA InfoNCE: rowsum/colsum/diag of exp(ng·ns^T/T) =================
__global__ void infonce_mfma_kernel(const u16* __restrict__ Ab, const u16* __restrict__ Bb,
                                    float* __restrict__ rowsum, float* __restrict__ colsum,
                                    float* __restrict__ pos) {
    __shared__ u16 Al[128 * 72];   // padded pitch 72 bf16 = 144 B
    __shared__ u16 Bl[128 * 72];
    int tid = threadIdx.x;
    int i0 = blockIdx.x * 128, j0 = blockIdx.y * 128;
    // stage 128x64 bf16 tiles (zero-fill OOB rows)
    const uint4 zero4 = make_uint4(0, 0, 0, 0);
    for (int u = tid; u < 1024; u += 256) {
        int row = u >> 3, ch = u & 7;
        int ga = i0 + row, gb = j0 + row;
        uint4 va = (ga < PN) ? ((const uint4*)Ab)[(size_t)ga * 8 + ch] : zero4;
        uint4 vb = (gb < PN) ? ((const uint4*)Bb)[(size_t)gb * 8 + ch] : zero4;
        ((uint4*)Al)[row * 9 + ch] = va;
        ((uint4*)Bl)[row * 9 + ch] = vb;
    }
    __syncthreads();
    int wv = tid >> 6, lane = tid & 63;
    int wr = (wv & 1) * 64;   // wave's row offset in block tile
    int wc = (wv >> 1) * 64;  // wave's col offset
    int quad = lane >> 4, l15 = lane & 15;

    short8 af[4][2], bf[4][2];
#pragma unroll
    for (int t = 0; t < 4; t++)
#pragma unroll
        for (int ks = 0; ks < 2; ks++) {
            af[t][ks] = *(const short8*)&Al[(wr + t * 16 + l15) * 72 + ks * 32 + quad * 8];
            bf[t][ks] = *(const short8*)&Bl[(wc + t * 16 + l15) * 72 + ks * 32 + quad * 8];
        }
    f32x4 acc[4][4];
#pragma unroll
    for (int rt = 0; rt < 4; rt++)
#pragma unroll
        for (int ct = 0; ct < 4; ct++) {
            f32x4 c = {0.f, 0.f, 0.f, 0.f};
            c = __builtin_amdgcn_mfma_f32_16x16x32_bf16(af[rt][0], bf[ct][0], c, 0, 0, 0);
            c = __builtin_amdgcn_mfma_f32_16x16x32_bf16(af[rt][1], bf[ct][1], c, 0, 0, 0);
            acc[rt][ct] = c;
        }
    // epilogue: e = exp(s/T); rowsums, colsums, diag
    float rs[4][4];
    float cs[4] = {0.f, 0.f, 0.f, 0.f};
#pragma unroll
    for (int rt = 0; rt < 4; rt++)
#pragma unroll
        for (int g = 0; g < 4; g++) rs[rt][g] = 0.f;

#pragma unroll
    for (int rt = 0; rt < 4; rt++) {
        int ibase = i0 + wr + rt * 16 + quad * 4;
#pragma unroll
        for (int ct = 0; ct < 4; ct++) {
            int j = j0 + wc + ct * 16 + l15;
            bool jv = (j < PN);
            float csum = 0.f;
#pragma unroll
            for (int g = 0; g < 4; g++) {
                int i = ibase + g;
                float e = 0.f;
                if (jv && i < PN) {
                    e = __expf(acc[rt][ct][g] * INV_T);
                    if (i == j) pos[i] = e;
                }
                rs[rt][g] += e;
                csum += e;
            }
            cs[ct] += csum;
        }
    }
    // reduce row sums across the 16 lanes sharing rows (xor 1,2,4,8)
#pragma unroll
    for (int off = 1; off <= 8; off <<= 1)
#pragma unroll
        for (int rt = 0; rt < 4; rt++)
#pragma unroll
            for (int g = 0; g < 4; g++) rs[rt][g] += __shfl_xor(rs[rt][g], off, 64);
    if (l15 == 0) {
#pragma unroll
        for (int rt = 0; rt < 4; rt++)
#pragma unroll
            for (int g = 0; g < 4; g++) {
                int i = i0 + wr + rt * 16 + quad * 4 + g;
                if (i < PN) atomicAdd(&rowsum[i], rs[rt][g]);
            }
    }
    // reduce col sums across quads (xor 16,32)
#pragma unroll
    for (int off = 16; off <= 32; off <<= 1)
#pragma unroll
        for (int ct = 0; ct < 4; ct++) cs[ct] += __shfl_xor(cs[ct], off, 64);
    if (quad == 0) {
#pragma unroll
        for (int ct = 0; ct < 4; ct++) {
            int j = j0 + wc + ct * 16 + l15;
            if (j < PN) atomicAdd(&colsum[j], cs[ct]);
        }
    }
}

// ---------------- f32 InfoNCE fallback (R3)
__global__ __launch_bounds__(256, 4) void infonce_kernel(
        const float* __restrict__ A, const float* __restrict__ B,
        float* __restrict__ rowsum, float* __restrict__ colsum, float* __restrict__ pos) {
    __shared__ float4 Bs[128 * 16];
    int tid = threadIdx.x;
    int i = blockIdx.x * 256 + tid;
    int j0 = blockIdx.y * 128;
    bool iv = (i < PN);
    float a[64];
    {
        const float4* A4 = (const float4*)(A + (size_t)i * 64);
#pragma unroll
        for (int k4 = 0; k4 < 16; k4++) {
            float4 t = iv ? A4[k4] : make_float4(0.f, 0.f, 0.f, 0.f);
            a[k4 * 4 + 0] = t.x; a[k4 * 4 + 1] = t.y; a[k4 * 4 + 2] = t.z; a[k4 * 4 + 3] = t.w;
        }
    }
    for (int t = tid; t < 2048; t += 256) {
        int row = t >> 4, kk = t & 15;
        int j = j0 + row;
        Bs[t] = (j < PN) ? ((const float4*)(B + (size_t)j * 64))[kk] : make_float4(0.f, 0.f, 0.f, 0.f);
    }
    __syncthreads();
    int lane = tid & 63;
    float rsum = 0.0f;
    int jmax = min(128, PN - j0);
    for (int c = 0; c < jmax; c++) {
        float s0 = 0.f, s1 = 0.f, s2 = 0.f, s3 = 0.f;
#pragma unroll
        for (int kk = 0; kk < 16; kk++) {
            float4 b4 = Bs[c * 16 + kk];
            s0 += a[kk * 4 + 0] * b4.x;
            s1 += a[kk * 4 + 1] * b4.y;
            s2 += a[kk * 4 + 2] * b4.z;
            s3 += a[kk * 4 + 3] * b4.w;
        }
        float s = (s0 + s1) + (s2 + s3);
        float e = iv ? __expf(s * INV_T) : 0.0f;
        rsum += e;
        int jc = j0 + c;
        if (iv && jc == i) pos[i] = e;
        float wsum = e;
#pragma unroll
        for (int off = 32; off > 0; off >>= 1) wsum += __shfl_xor(wsum, off, 64);
        if (lane == 0) atomicAdd(&colsum[jc], wsum);
    }
    if (iv) atomicAdd(&rowsum[i], rsum);
}

// ---------------- hg_users: msg_emb + ue + msg_emb*ue; safe when hg aliases mp
__global__ void fuse_users_kernel(const float* __restrict__ mg, const float* __restrict__ ms,
                                  const float* __restrict__ mp, const float* __restrict__ fw,
                                  const float* __restrict__ fb, const float* __restrict__ ue,
                                  float* __restrict__ hg) {
    __shared__ float G[4][64], S[4][64], Pm[4][64];
    int tid = threadIdx.x;
    int u0 = blockIdx.x * 4;
    {
        int r = tid >> 6, k = tid & 63;
        int o = (u0 + r) * 64 + k;
        G[r][k] = mg[o]; S[r][k] = ms[o]; Pm[r][k] = mp[o];
    }
    __syncthreads();
    int r = tid >> 6, j = tid & 63;
    float acc = fb[j];
    for (int k = 0; k < 64; k++) {
        float g = G[r][k], s = S[r][k], p = Pm[r][k];
        float gs = g * s, gp = g * p, sp = s * p, gsp = gs * p;
        acc += g   * fw[(0 * 64 + k) * 64 + j];
        acc += s   * fw[(1 * 64 + k) * 64 + j];
        acc += p   * fw[(2 * 64 + k) * 64 + j];
        acc += gs  * fw[(3 * 64 + k) * 64 + j];
        acc += gp  * fw[(4 * 64 + k) * 64 + j];
        acc += sp  * fw[(5 * 64 + k) * 64 + j];
        acc += gsp * fw[(6 * 64 + k) * 64 + j];
    }
    int o = (u0 + r) * 64 + j;
    float u = ue[o];
    hg[o] = acc + u + acc * u;
}

__global__ void fusion_out_kernel(const float* __restrict__ hgp, const float* __restrict__ ng,
                                  const float* __restrict__ ns, float* __restrict__ fp,
                                  float* __restrict__ outp) {
    int lane = threadIdx.x & 63;
    int row = (blockIdx.x * blockDim.x + threadIdx.x) >> 6;
    if (row >= PN) return;
    int o = row * 64 + lane;
    float v = hgp[o];
    float s = v * v;
#pragma unroll
    for (int off = 32; off > 0; off >>= 1) s += __shfl_xor(s, off, 64);
    float d = fmaxf(sqrtf(s), 1e-12f);
    float f = v / d + ng[o] + ns[o];
    fp[o] = f;
    outp[o] = f;
}

__global__ void batch_out_kernel(const float* __restrict__ us, const int* __restrict__ idx,
                                 float* __restrict__ outp) {
    int lane = threadIdx.x & 63;
    int b = (blockIdx.x * blockDim.x + threadIdx.x) >> 6;
    if (b >= BN) return;
    int r = idx[b];
    float v = us[r * 64 + lane];
    float s = v * v;
#pragma unroll
    for (int off = 32; off > 0; off >>= 1) s += __shfl_xor(s, off, 64);
    float d = fmaxf(sqrtf(s), 1e-12f);
    outp[b * 64 + lane] = v / d;
}

__global__ void loss_kernel(const float* __restrict__ pos, const float* __restrict__ n1,
                            const float* __restrict__ n2, float* __restrict__ outp) {
    __shared__ float red[256];
    int tid = threadIdx.x;
    float acc = 0.0f;
    for (int i = tid; i < PN; i += 256) {
        float p = pos[i];
        acc += -logf(p / (n1[i] + 1e-8f) + 1e-8f);
        acc += -logf(p / (n2[i] + 1e-8f) + 1e-8f);
    }
    red[tid] = acc;
    __syncthreads();
    for (int s = 128; s > 0; s >>= 1) {
        if (tid < s) red[tid] += red[tid + s];
        __syncthreads();
    }
    if (tid == 0) outp[0] = 0.5f * red[0] / (float)PN;
}

extern "C" void kernel_launch(void* const* d_in, const int* in_sizes, int n_in,
                              void* d_out, int out_size, void* d_ws, size_t ws_size,
                              hipStream_t stream) {
    (void)in_sizes; (void)n_in; (void)out_size;
    const float* poi  = (const float*)d_in[0];
    const float* uemb = (const float*)d_in[1];
    const float* wgg  = (const float*)d_in[2];
    const float* bgg  = (const float*)d_in[3];
    const float* wgs  = (const float*)d_in[4];
    const float* bgs  = (const float*)d_in[5];
    const float* wgc  = (const float*)d_in[6];
    const float* bgc  = (const float*)d_in[7];
    const float* fw   = (const float*)d_in[8];
    const float* fb   = (const float*)d_in[9];
    const float* geo_vals = (const float*)d_in[10];
    const float* src_vals = (const float*)d_in[11];
    const float* tar_vals = (const float*)d_in[12];
    const float* up_vals  = (const float*)d_in[13];
    const float* pu_vals  = (const float*)d_in[14];
    const int* geo_rows = (const int*)d_in[15];
    const int* geo_cols = (const int*)d_in[16];
    const int* src_rows = (const int*)d_in[17];
    const int* src_cols = (const int*)d_in[18];
    const int* tar_rows = (const int*)d_in[19];
    const int* tar_cols = (const int*)d_in[20];
    const int* up_rows  = (const int*)d_in[21];
    const int* up_cols  = (const int*)d_in[22];
    const int* pu_rows  = (const int*)d_in[23];
    const int* pu_cols  = (const int*)d_in[24];
    const int* user_idx = (const int*)d_in[25];

    const int PD = PN * 64, UD = UN * 64;
    const size_t PDB = (size_t)PD * sizeof(float);
    const size_t UDB = (size_t)UD * sizeof(float);

    // ---- workspace layout
    float* F = (float*)d_ws;
    float* rowsum = F;                  // PN
    float* colsum = rowsum + PN;        // PN
    float* pos    = colsum + PN;        // PN
    u16*   ngb    = (u16*)(F + 3 * PN); // PD bf16
    u16*   nsb    = ngb + PD;           // PD bf16
    float* U0     = F + 3 * PN + PD;    // UD
    float* P0     = U0 + UD;
    float* P1     = P0 + PD;
    float* P2     = P1 + PD;
    float* P3     = P2 + PD;
    float* P4     = P3 + PD;
    size_t base_bytes = (size_t)(3 * PN + PD + UD + 5 * PD) * 4;

    int* M = (int*)(P4 + PD);           // CSR meta
    int* geo_rp = M;               int* geo_cur = geo_rp + PN + 1;
    int* tar_rp = geo_cur + PN;    int* tar_cur = tar_rp + PN + 1;
    int* src_rp = tar_cur + PN;    int* src_cur = src_rp + PN + 1;
    int* up_rp  = src_cur + PN;    int* up_cur  = up_rp + UN + 1;
    int* pu_rp  = up_cur + UN;     int* pu_cur  = pu_rp + PN + 1;
    const size_t meta_ints = 96006;     // padded even
    int2* geo_ent = (int2*)(M + meta_ints);
    int2* tar_ent = geo_ent + NGE;
    int2* src_ent = tar_ent + NDE;
    int2* up_ent  = src_ent + NDE;
    int2* pu_ent  = up_ent + NUE;
    size_t csr_bytes = (meta_ints + 2ull * (NGE + NDE + NDE + NUE + NPUE)) * 4;

    bool pathA = ws_size >= base_bytes + csr_bytes;   // CSR + MFMA
    bool pathB = !pathA && ws_size >= base_bytes;     // atomic + MFMA

    float* out_bu = (float*)d_out;
    float* out_fp = out_bu + (size_t)BN * 64;
    float* out_loss = out_fp + (size_t)PN * 64;

    const int n4 = PD / 4, EB = 625, SG = 4096, RB = PN / 4;

    (void)hipMemsetAsync(rowsum, 0, 3 * (size_t)PN * sizeof(float), stream);

    if (pathA) {
        // ---- build 5 CSRs
        (void)hipMemsetAsync(M, 0, meta_ints * 4, stream);
        hist_kernel<<<(NGE + 255) / 256, 256, 0, stream>>>(geo_rows, geo_cur, NGE);
        scan_kernel<<<1, 1024, 0, stream>>>(geo_cur, geo_rp, PN, NGE);
        scatter_kernel<<<(NGE + 255) / 256, 256, 0, stream>>>(geo_rows, geo_cols, geo_vals, geo_cur, geo_ent, NGE);
        hist_kernel<<<(NDE + 255) / 256, 256, 0, stream>>>(tar_rows, tar_cur, NDE);
        scan_kernel<<<1, 1024, 0, stream>>>(tar_cur, tar_rp, PN, NDE);
        scatter_kernel<<<(NDE + 255) / 256, 256, 0, stream>>>(tar_rows, tar_cols, tar_vals, tar_cur, tar_ent, NDE);
        hist_kernel<<<(NDE + 255) / 256, 256, 0, stream>>>(src_rows, src_cur, NDE);
        scan_kernel<<<1, 1024, 0, stream>>>(src_cur, src_rp, PN, NDE);
        scatter_kernel<<<(NDE + 255) / 256, 256, 0, stream>>>(src_rows, src_cols, src_vals, src_cur, src_ent, NDE);
        hist_kernel<<<(NUE + 255) / 256, 256, 0, stream>>>(up_rows, up_cur, NUE);
        scan_kernel<<<1, 1024, 0, stream>>>(up_cur, up_rp, UN, NUE);
        scatter_kernel<<<(NUE + 255) / 256, 256, 0, stream>>>(up_rows, up_cols, up_vals, up_cur, up_ent, NUE);
        hist_kernel<<<(NPUE + 255) / 256, 256, 0, stream>>>(pu_rows, pu_cur, NPUE);
        scan_kernel<<<1, 1024, 0, stream>>>(pu_cur, pu_rp, PN, NPUE);
        scatter_kernel<<<(NPUE + 255) / 256, 256, 0, stream>>>(pu_rows, pu_cols, pu_vals, pu_cur, pu_ent, NPUE);

        // ---- geo chain
        gate_kernel<<<RB, 256, 0, stream>>>(poi, wgg, bgg, P0);
        spmm_csr_kernel<<<RB, 256, 0, stream>>>(geo_rp, geo_ent, P0, P0, P1, PN);   // x1
        spmm_csr_kernel<<<RB, 256, 0, stream>>>(geo_rp, geo_ent, P1, P1, P2, PN);   // x2
        avg_norm_kernel<<<RB, 256, 0, stream>>>(P0, P1, P2, P2, ngb, PN);           // ng

        // ---- seq chain
        gate_kernel<<<RB, 256, 0, stream>>>(poi, wgs, bgs, P0);
        spmm_csr_kernel<<<RB, 256, 0, stream>>>(tar_rp, tar_ent, P0, nullptr, P1, PN); // m1
        spmm_csr_kernel<<<RB, 256, 0, stream>>>(src_rp, src_ent, P1, P0, P3, PN);      // x1
        spmm_csr_kernel<<<RB, 256, 0, stream>>>(tar_rp, tar_ent, P3, nullptr, P1, PN); // m2
        spmm_csr_kernel<<<RB, 256, 0, stream>>>(src_rp, src_ent, P1, P3, P4, PN);      // x2
        avg_norm_kernel<<<RB, 256, 0, stream>>>(P0, P3, P4, P4, nsb, PN);              // ns

        // ---- InfoNCE (MFMA)
        dim3 ig(79, 79);
        infonce_mfma_kernel<<<ig, 256, 0, stream>>>(ngb, nsb, rowsum, colsum, pos);

        // ---- multi-view fold
        gate_kernel<<<RB, 256, 0, stream>>>(poi, wgc, bgc, P0);                        // col_g
        spmm3_csr_kernel<<<UN / 4, 256, 0, stream>>>(up_rp, up_ent, P2, P4, P0,
                                                     P1, P3, U0, UN);
        fuse_users_kernel<<<UN / 4, 256, 0, stream>>>(P1, P3, U0, fw, fb, uemb, U0);
        spmm_csr_kernel<<<RB, 256, 0, stream>>>(pu_rp, pu_ent, U0, P0, P1, PN);        // hg_pois

        // ---- outputs
        fusion_out_kernel<<<RB, 256, 0, stream>>>(P1, P2, P4, P3, out_fp);
        spmm_csr_kernel<<<(UN + 3) / 4, 256, 0, stream>>>(up_rp, up_ent, P3, nullptr, U0, UN);
        batch_out_kernel<<<BN / 4, 256, 0, stream>>>(U0, user_idx, out_bu);
        loss_kernel<<<1, 256, 0, stream>>>(pos, rowsum, colsum, out_loss);
    } else {
        u16* ngb_p = pathB ? ngb : nullptr;
        u16* nsb_p = pathB ? nsb : nullptr;
        // fallback: atomic SpMM (R3 structure); U0/P pools shifted only if pathB
        float* fU0 = pathB ? U0 : (F + 3 * PN);
        float* fP0 = fU0 + UD;
        float* fP1 = fP0 + PD;
        float* fP2 = fP1 + PD;
        float* fP3 = fP2 + PD;
        float* fP4 = fP3 + PD;

        gate_kernel<<<RB, 256, 0, stream>>>(poi, wgg, bgg, fP0);
        (void)hipMemsetAsync(fP1, 0, PDB, stream);
        spmm_kernel<<<SG, 256, 0, stream>>>(geo_rows, geo_cols, geo_vals, fP0, fP1, NGE);
        add_in_kernel<<<EB, 256, 0, stream>>>((float4*)fP1, (const float4*)fP0, n4);
        (void)hipMemsetAsync(fP2, 0, PDB, stream);
        spmm_kernel<<<SG, 256, 0, stream>>>(geo_rows, geo_cols, geo_vals, fP1, fP2, NGE);
        add_in_kernel<<<EB, 256, 0, stream>>>((float4*)fP2, (const float4*)fP1, n4);
        avg_norm_kernel<<<RB, 256, 0, stream>>>(fP0, fP1, fP2, fP2, ngb_p, PN);

        gate_kernel<<<RB, 256, 0, stream>>>(poi, wgs, bgs, fP0);
        (void)hipMemsetAsync(fP1, 0, PDB, stream);
        spmm_kernel<<<SG, 256, 0, stream>>>(tar_rows, tar_cols, tar_vals, fP0, fP1, NDE);
        (void)hipMemsetAsync(fP3, 0, PDB, stream);
        spmm_kernel<<<SG, 256, 0, stream>>>(src_rows, src_cols, src_vals, fP1, fP3, NDE);
        add_in_kernel<<<EB, 256, 0, stream>>>((float4*)fP3, (const float4*)fP0, n4);
        (void)hipMemsetAsync(fP1, 0, PDB, stream);
        spmm_kernel<<<SG, 256, 0, stream>>>(tar_rows, tar_cols, tar_vals, fP3, fP1, NDE);
        (void)hipMemsetAsync(fP4, 0, PDB, stream);
        spmm_kernel<<<SG, 256, 0, stream>>>(src_rows, src_cols, src_vals, fP1, fP4, NDE);
        add_in_kernel<<<EB, 256, 0, stream>>>((float4*)fP4, (const float4*)fP3, n4);
        avg_norm_kernel<<<RB, 256, 0, stream>>>(fP0, fP3, fP4, fP4, nsb_p, PN);

        if (pathB) {
            dim3 ig(79, 79);
            infonce_mfma_kernel<<<ig, 256, 0, stream>>>(ngb, nsb, rowsum, colsum, pos);
        } else {
            dim3 ig(40, 79);
            infonce_kernel<<<ig, 256, 0, stream>>>(fP2, fP4, rowsum, colsum, pos);
        }

        gate_kernel<<<RB, 256, 0, stream>>>(poi, wgc, bgc, fP0);
        (void)hipMemsetAsync(fP1, 0, UDB, stream);
        (void)hipMemsetAsync(fP3, 0, UDB, stream);
        (void)hipMemsetAsync(fU0, 0, UDB, stream);
        spmm3_kernel<<<SG, 256, 0, stream>>>(up_rows, up_cols, up_vals, fP2, fP4, fP0,
                                             fP1, fP3, fU0, NUE);
        fuse_users_kernel<<<UN / 4, 256, 0, stream>>>(fP1, fP3, fU0, fw, fb, uemb, fU0);
        (void)hipMemsetAsync(fP1, 0, PDB, stream);
        spmm_kernel<<<SG, 256, 0, stream>>>(pu_rows, pu_cols, pu_vals, fU0, fP1, NPUE);
        add_in_kernel<<<EB, 256, 0, stream>>>((float4*)fP1, (const float4*)fP0, n4);

        fusion_out_kernel<<<RB, 256, 0, stream>>>(fP1, fP2, fP4, fP3, out_fp);
        (void)hipMemsetAsync(fU0, 0, UDB, stream);
        spmm_kernel<<<SG, 256, 0, stream>>>(up_rows, up_cols, up_vals, fP3, fU0, NUE);
        batch_out_kernel<<<BN / 4, 256, 0, stream>>>(fU0, user_idx, out_bu);
        loss_kernel<<<1, 256, 0, stream>>>(pos, rowsum, colsum, out_loss);
    }
}

// Round 7
// 589.307 us; speedup vs baseline: 2.6079x; 1.3045x over previous
//
#include <hip/hip_runtime.h>

#define PN 10000
#define UN 8000
#define BN 4096
#define NGE 320000
#define NDE 320000
#define NUE 400000
#define NPUE 400000
#define INV_T 5.0f
// cumulative edge offsets: geo, tar, src, up, pu
#define E0 320000
#define E1 640000
#define E2 960000
#define E3 1360000
#define E4 1760000

typedef __attribute__((ext_vector_type(8))) short short8;
typedef __attribute__((ext_vector_type(4))) float f32x4;
typedef unsigned short u16;
typedef unsigned int u32;

__device__ __forceinline__ u16 f2bf(float x) {
    u32 u = __float_as_uint(x);
    return (u16)((u + 0x7FFFu + ((u >> 16) & 1u)) >> 16);
}

// ---------------- zero stats + CSR counters in one dispatch
__global__ void zero_kernel(float* __restrict__ a, int na, int* __restrict__ b, int nb) {
    int i = blockIdx.x * 256 + threadIdx.x;
    if (i < na) a[i] = 0.0f;
    else {
        int j = i - na;
        if (j < nb) b[j] = 0;
    }
}

// ---------------- all 3 gates: out = pe * sigmoid(pe @ W + b)  (ALL outputs PD-sized)
__global__ void gates3_kernel(const float* __restrict__ poi,
                              const float* __restrict__ w0, const float* __restrict__ b0,
                              const float* __restrict__ w1, const float* __restrict__ b1,
                              const float* __restrict__ w2, const float* __restrict__ b2,
                              float* __restrict__ o0, float* __restrict__ o1, float* __restrict__ o2) {
    __shared__ float W[3][64][64];
    __shared__ float Bv[3][64];
    __shared__ float pe[4][64];
    int tid = threadIdx.x;
    for (int t = tid; t < 4096; t += 256) {
        int k = t >> 6, j = t & 63;
        W[0][k][j] = w0[t]; W[1][k][j] = w1[t]; W[2][k][j] = w2[t];
    }
    if (tid < 64) { Bv[0][tid] = b0[tid]; Bv[1][tid] = b1[tid]; Bv[2][tid] = b2[tid]; }
    int r0 = blockIdx.x * 4;
    {
        int r = tid >> 6, k = tid & 63;
        pe[r][k] = poi[(r0 + r) * 64 + k];
    }
    __syncthreads();
    int r = tid >> 6, j = tid & 63;
    float pj = pe[r][j];
    int o = (r0 + r) * 64 + j;
    float out[3];
#pragma unroll
    for (int g = 0; g < 3; g++) {
        float acc = Bv[g][j];
#pragma unroll
        for (int k = 0; k < 64; k++) acc += pe[r][k] * W[g][k][j];
        out[g] = pj * (1.0f / (1.0f + __expf(-acc)));
    }
    o0[o] = out[0]; o1[o] = out[1]; o2[o] = out[2];
}

// ================= CSR build: all 5 matrices per dispatch =================
__global__ void hist_all_kernel(const int* __restrict__ r0, const int* __restrict__ r1,
                                const int* __restrict__ r2, const int* __restrict__ r3,
                                const int* __restrict__ r4,
                                int* __restrict__ c0, int* __restrict__ c1, int* __restrict__ c2,
                                int* __restrict__ c3, int* __restrict__ c4) {
    int e = blockIdx.x * 256 + threadIdx.x;
    if (e < E0)      atomicAdd(&c0[r0[e]], 1);
    else if (e < E1) atomicAdd(&c1[r1[e - E0]], 1);
    else if (e < E2) atomicAdd(&c2[r2[e - E1]], 1);
    else if (e < E3) atomicAdd(&c3[r3[e - E2]], 1);
    else if (e < E4) atomicAdd(&c4[r4[e - E3]], 1);
}

__global__ void scan_all_kernel(int* c0, int* p0, int n0, int z0,
                                int* c1, int* p1, int n1, int z1,
                                int* c2, int* p2, int n2, int z2,
                                int* c3, int* p3, int n3, int z3,
                                int* c4, int* p4, int n4, int z4) {
    __shared__ int part[1024];
    int* cnt; int* rp; int n; int nnz;
    switch (blockIdx.x) {
        case 0: cnt = c0; rp = p0; n = n0; nnz = z0; break;
        case 1: cnt = c1; rp = p1; n = n1; nnz = z1; break;
        case 2: cnt = c2; rp = p2; n = n2; nnz = z2; break;
        case 3: cnt = c3; rp = p3; n = n3; nnz = z3; break;
        default: cnt = c4; rp = p4; n = n4; nnz = z4; break;
    }
    int tid = threadIdx.x;
    int chunk = (n + 1023) >> 10;
    int base = tid * chunk;
    int s = 0;
    for (int k = 0; k < chunk; k++) {
        int i = base + k;
        if (i < n) s += cnt[i];
    }
    part[tid] = s;
    __syncthreads();
    for (int off = 1; off < 1024; off <<= 1) {
        int v = (tid >= off) ? part[tid - off] : 0;
        __syncthreads();
        part[tid] += v;
        __syncthreads();
    }
    int pre = (tid > 0) ? part[tid - 1] : 0;
    for (int k = 0; k < chunk; k++) {
        int i = base + k;
        if (i < n) {
            int c = cnt[i];
            rp[i] = pre;
            cnt[i] = pre;   // becomes cursor
            pre += c;
        }
    }
    if (tid == 0) rp[n] = nnz;
}

__global__ void scatter_all_kernel(
        const int* __restrict__ r0, const int* __restrict__ k0, const float* __restrict__ v0, int* u0, int2* e0,
        const int* __restrict__ r1, const int* __restrict__ k1, const float* __restrict__ v1, int* u1, int2* e1,
        const int* __restrict__ r2, const int* __restrict__ k2, const float* __restrict__ v2, int* u2, int2* e2,
        const int* __restrict__ r3, const int* __restrict__ k3, const float* __restrict__ v3, int* u3, int2* e3,
        const int* __restrict__ r4, const int* __restrict__ k4, const float* __restrict__ v4, int* u4, int2* e4) {
    int e = blockIdx.x * 256 + threadIdx.x;
    const int* rr; const int* kk; const float* vv; int* cu; int2* en; int idx;
    if (e < E0)      { rr = r0; kk = k0; vv = v0; cu = u0; en = e0; idx = e; }
    else if (e < E1) { rr = r1; kk = k1; vv = v1; cu = u1; en = e1; idx = e - E0; }
    else if (e < E2) { rr = r2; kk = k2; vv = v2; cu = u2; en = e2; idx = e - E1; }
    else if (e < E3) { rr = r3; kk = k3; vv = v3; cu = u3; en = e3; idx = e - E2; }
    else if (e < E4) { rr = r4; kk = k4; vv = v4; cu = u4; en = e4; idx = e - E3; }
    else return;
    int p = atomicAdd(&cu[rr[idx]], 1);
    en[p] = make_int2(kk[idx], __float_as_int(vv[idx]));
}

// ================= multi-job CSR SpMM (wave per row) =================
// ALIAS RULES: y may alias add/avg_a/avg_b (element-wise same-thread read->write);
//              y must NEVER alias x (scattered cross-row reads).
struct SpmmJob {
    const int* rp; const int2* ent; const float* x; const float* add;
    const float* avg_a; const float* avg_b; float* y; u16* yb;
    int nrows; int mode;   // mode 0: y=acc(+add); mode 1: + avg3+l2norm+bf16
};

__global__ void spmm_jobs_kernel(SpmmJob ja, SpmmJob jb, int nb0) {
    bool first = ((int)blockIdx.x < nb0);
    SpmmJob J; int blk;
    if (first) { J = ja; blk = blockIdx.x; }
    else       { J = jb; blk = blockIdx.x - nb0; }
    int lane = threadIdx.x & 63;
    int row = blk * 4 + (threadIdx.x >> 6);
    if (row >= J.nrows) return;
    size_t o = (size_t)row * 64 + lane;
    int s = J.rp[row], e = J.rp[row + 1];
    float acc = J.add ? J.add[o] : 0.0f;
    int p = s;
    for (; p + 4 <= e; p += 4) {
        int2 c0 = J.ent[p], c1 = J.ent[p + 1], c2 = J.ent[p + 2], c3 = J.ent[p + 3];
        float w0 = J.x[(size_t)c0.x * 64 + lane];
        float w1 = J.x[(size_t)c1.x * 64 + lane];
        float w2 = J.x[(size_t)c2.x * 64 + lane];
        float w3 = J.x[(size_t)c3.x * 64 + lane];
        acc = fmaf(__int_as_float(c0.y), w0, acc);
        acc = fmaf(__int_as_float(c1.y), w1, acc);
        acc = fmaf(__int_as_float(c2.y), w2, acc);
        acc = fmaf(__int_as_float(c3.y), w3, acc);
    }
    for (; p < e; ++p) {
        int2 c = J.ent[p];
        acc = fmaf(__int_as_float(c.y), J.x[(size_t)c.x * 64 + lane], acc);
    }
    if (J.mode == 0) { J.y[o] = acc; return; }
    // avg3 + l2norm + bf16 epilogue
    float v = (J.avg_a[o] + J.avg_b[o] + acc) * (1.0f / 3.0f);
    float ss = v * v;
#pragma unroll
    for (int off = 32; off > 0; off >>= 1) ss += __shfl_xor(ss, off, 64);
    float d = fmaxf(sqrtf(ss), 1e-12f);
    float r = v / d;
    J.y[o] = r;
    J.yb[o] = f2bf(r);
}

// ================= spmm3 over up + fuse_users epilogue =================
__global__ void spmm3_fuse_kernel(const int* __restrict__ rp, const int2* __restrict__ ent,
                                  const float* __restrict__ x0, const float* __restrict__ x1,
                                  const float* __restrict__ x2, const float* __restrict__ fw,
                                  const float* __restrict__ fb, const float* __restrict__ ue,
                                  float* __restrict__ hg) {
    __shared__ float msg[4][448];
    int tid = threadIdx.x, lane = tid & 63, r = tid >> 6;
    int row = blockIdx.x * 4 + r;
    float a0 = 0.f, a1 = 0.f, a2 = 0.f;
    {
        int s = rp[row], e = rp[row + 1];
        for (int p = s; p < e; ++p) {
            int2 c = ent[p];
            float v = __int_as_float(c.y);
            size_t o = (size_t)c.x * 64 + lane;
            a0 = fmaf(v, x0[o], a0);
            a1 = fmaf(v, x1[o], a1);
            a2 = fmaf(v, x2[o], a2);
        }
    }
    msg[r][0 * 64 + lane] = a0;
    msg[r][1 * 64 + lane] = a1;
    msg[r][2 * 64 + lane] = a2;
    msg[r][3 * 64 + lane] = a0 * a1;
    msg[r][4 * 64 + lane] = a0 * a2;
    msg[r][5 * 64 + lane] = a1 * a2;
    msg[r][6 * 64 + lane] = a0 * a1 * a2;
    __syncthreads();
    float acc = fb[lane];
#pragma unroll 8
    for (int k = 0; k < 448; k++) acc = fmaf(msg[r][k], fw[k * 64 + lane], acc);
    size_t o = (size_t)row * 64 + lane;
    float u = ue[o];
    hg[o] = acc + u + acc * u;
}

// ================= pu spmm + col_g add + fusion_out epilogue =================
__global__ void pu_out_kernel(const int* __restrict__ rp, const int2* __restrict__ ent,
                              const float* __restrict__ hg, const float* __restrict__ colg,
                              const float* __restrict__ ng, const float* __restrict__ ns,
                              float* __restrict__ fuse, float* __restrict__ outp) {
    int lane = threadIdx.x & 63;
    int row = blockIdx.x * 4 + (threadIdx.x >> 6);
    size_t o = (size_t)row * 64 + lane;
    float acc = colg[o];
    int s = rp[row], e = rp[row + 1];
    int p = s;
    for (; p + 4 <= e; p += 4) {
        int2 c0 = ent[p], c1 = ent[p + 1], c2 = ent[p + 2], c3 = ent[p + 3];
        float w0 = hg[(size_t)c0.x * 64 + lane];
        float w1 = hg[(size_t)c1.x * 64 + lane];
        float w2 = hg[(size_t)c2.x * 64 + lane];
        float w3 = hg[(size_t)c3.x * 64 + lane];
        acc = fmaf(__int_as_float(c0.y), w0, acc);
        acc = fmaf(__int_as_float(c1.y), w1, acc);
        acc = fmaf(__int_as_float(c2.y), w2, acc);
        acc = fmaf(__int_as_float(c3.y), w3, acc);
    }
    for (; p < e; ++p) {
        int2 c = ent[p];
        acc = fmaf(__int_as_float(c.y), hg[(size_t)c.x * 64 + lane], acc);
    }
    float ss = acc * acc;
#pragma unroll
    for (int off = 32; off > 0; off >>= 1) ss += __shfl_xor(ss, off, 64);
    float d = fmaxf(sqrtf(ss), 1e-12f);
    float f = acc / d + ng[o] + ns[o];
    fuse[o] = f;
    outp[o] = f;
}

// ================= MFMA InfoNCE with specialized epilogue =================
__global__ __launch_bounds__(256) void infonce_mfma_kernel(
        const u16* __restrict__ Ab, const u16* __restrict__ Bb,
        float* __restrict__ rowsum, float* __restrict__ colsum, float* __restrict__ pos) {
    __shared__ __align__(16) char smraw[36864];
    u16* Al = (u16*)smraw;              // 128 rows * 72 pitch = 18432 B
    u16* Bl = (u16*)(smraw + 18432);
    float* red = (float*)smraw;         // reused: [32 slots][131 pitch] = 16768 B
    int tid = threadIdx.x;
    int i0 = blockIdx.x * 128, j0 = blockIdx.y * 128;
    const uint4 zero4 = make_uint4(0, 0, 0, 0);
    for (int u = tid; u < 1024; u += 256) {
        int row = u >> 3, ch = u & 7;
        int ga = i0 + row, gb = j0 + row;
        uint4 va = (ga < PN) ? ((const uint4*)Ab)[(size_t)ga * 8 + ch] : zero4;
        uint4 vb = (gb < PN) ? ((const uint4*)Bb)[(size_t)gb * 8 + ch] : zero4;
        ((uint4*)Al)[row * 9 + ch] = va;
        ((uint4*)Bl)[row * 9 + ch] = vb;
    }
    __syncthreads();
    int wv = tid >> 6, lane = tid & 63;
    int wr = (wv & 1) * 64;
    int wc = (wv >> 1) * 64;
    int quad = lane >> 4, l15 = lane & 15;

    short8 af[4][2], bf[4][2];
#pragma unroll
    for (int t = 0; t < 4; t++)
#pragma unroll
        for (int ks = 0; ks < 2; ks++) {
            af[t][ks] = *(const short8*)&Al[(wr + t * 16 + l15) * 72 + ks * 32 + quad * 8];
            bf[t][ks] = *(const short8*)&Bl[(wc + t * 16 + l15) * 72 + ks * 32 + quad * 8];
        }
    __syncthreads();   // frags in regs; LDS reusable for reduction

    f32x4 acc[4][4];
#pragma unroll
    for (int rt = 0; rt < 4; rt++)
#pragma unroll
        for (int ct = 0; ct < 4; ct++) {
            f32x4 c = {0.f, 0.f, 0.f, 0.f};
            c = __builtin_amdgcn_mfma_f32_16x16x32_bf16(af[rt][0], bf[ct][0], c, 0, 0, 0);
            c = __builtin_amdgcn_mfma_f32_16x16x32_bf16(af[rt][1], bf[ct][1], c, 0, 0, 0);
            acc[rt][ct] = c;
        }

    float rs[4][4];
#pragma unroll
    for (int rt = 0; rt < 4; rt++)
#pragma unroll
        for (int g = 0; g < 4; g++) rs[rt][g] = 0.f;
    float cs[4] = {0.f, 0.f, 0.f, 0.f};

    bool interior = (i0 + 128 <= PN) && (j0 + 128 <= PN) && (i0 != j0);
    if (interior) {
#pragma unroll
        for (int rt = 0; rt < 4; rt++)
#pragma unroll
            for (int ct = 0; ct < 4; ct++) {
                float csum = 0.f;
#pragma unroll
                for (int g = 0; g < 4; g++) {
                    float e = __expf(acc[rt][ct][g] * INV_T);
                    rs[rt][g] += e;
                    csum += e;
                }
                cs[ct] += csum;
            }
    } else {
#pragma unroll
        for (int rt = 0; rt < 4; rt++) {
            int ibase = i0 + wr + rt * 16 + quad * 4;
#pragma unroll
            for (int ct = 0; ct < 4; ct++) {
                int j = j0 + wc + ct * 16 + l15;
                bool jv = (j < PN);
                float csum = 0.f;
#pragma unroll
                for (int g = 0; g < 4; g++) {
                    int i = ibase + g;
                    float e = 0.f;
                    if (jv && i < PN) {
                        e = __expf(acc[rt][ct][g] * INV_T);
                        if (i == j) pos[i] = e;
                    }
                    rs[rt][g] += e;
                    csum += e;
                }
                cs[ct] += csum;
            }
        }
    }
    // colsum: reduce across quads (xor 16,32), then 16 lanes atomic
#pragma unroll
    for (int off = 16; off <= 32; off <<= 1)
#pragma unroll
        for (int ct = 0; ct < 4; ct++) cs[ct] += __shfl_xor(cs[ct], off, 64);
    if (quad == 0) {
#pragma unroll
        for (int ct = 0; ct < 4; ct++) {
            int j = j0 + wc + ct * 16 + l15;
            if (j < PN) atomicAdd(&colsum[j], cs[ct]);
        }
    }
    // rowsum: LDS transpose reduce (slot = colgroup*16+l15, addr [slot][rowlocal])
    int slot = (wv >> 1) * 16 + l15;
#pragma unroll
    for (int rt = 0; rt < 4; rt++)
#pragma unroll
        for (int g = 0; g < 4; g++) {
            int rl = wr + rt * 16 + quad * 4 + g;
            red[slot * 131 + rl] = rs[rt][g];
        }
    __syncthreads();
    if (tid < 128) {
        float sum = 0.f;
#pragma unroll
        for (int s2 = 0; s2 < 32; s2++) sum += red[s2 * 131 + tid];
        int i = i0 + tid;
        if (i < PN) atomicAdd(&rowsum[i], sum);
    }
}

// ================= batch_out + loss in one dispatch =================
__global__ void batch_loss_kernel(const float* __restrict__ us, const int* __restrict__ idx,
                                  float* __restrict__ outb, const float* __restrict__ pos,
                                  const float* __restrict__ n1, const float* __restrict__ n2,
                                  float* __restrict__ outl) {
    __shared__ float red[256];
    int tid = threadIdx.x;
    if ((int)blockIdx.x < 1024) {
        int lane = tid & 63;
        int b = blockIdx.x * 4 + (tid >> 6);
        int r = idx[b];
        float v = us[(size_t)r * 64 + lane];
        float s = v * v;
#pragma unroll
        for (int off = 32; off > 0; off >>= 1) s += __shfl_xor(s, off, 64);
        float d = fmaxf(sqrtf(s), 1e-12f);
        outb[(size_t)b * 64 + lane] = v / d;
        return;
    }
    float acc = 0.0f;
    for (int i = tid; i < PN; i += 256) {
        float p = pos[i];
        acc += -logf(p / (n1[i] + 1e-8f) + 1e-8f);
        acc += -logf(p / (n2[i] + 1e-8f) + 1e-8f);
    }
    red[tid] = acc;
    __syncthreads();
    for (int s = 128; s > 0; s >>= 1) {
        if (tid < s) red[tid] += red[tid + s];
        __syncthreads();
    }
    if (tid == 0) outl[0] = 0.5f * red[0] / (float)PN;
}

extern "C" void kernel_launch(void* const* d_in, const int* in_sizes, int n_in,
                              void* d_out, int out_size, void* d_ws, size_t ws_size,
                              hipStream_t stream) {
    (void)in_sizes; (void)n_in; (void)out_size; (void)ws_size;
    const float* poi  = (const float*)d_in[0];
    const float* uemb = (const float*)d_in[1];
    const float* wgg  = (const float*)d_in[2];
    const float* bgg  = (const float*)d_in[3];
    const float* wgs  = (const float*)d_in[4];
    const float* bgs  = (const float*)d_in[5];
    const float* wgc  = (const float*)d_in[6];
    const float* bgc  = (const float*)d_in[7];
    const float* fw   = (const float*)d_in[8];
    const float* fb   = (const float*)d_in[9];
    const float* geo_vals = (const float*)d_in[10];
    const float* src_vals = (const float*)d_in[11];
    const float* tar_vals = (const float*)d_in[12];
    const float* up_vals  = (const float*)d_in[13];
    const float* pu_vals  = (const float*)d_in[14];
    const int* geo_rows = (const int*)d_in[15];
    const int* geo_cols = (const int*)d_in[16];
    const int* src_rows = (const int*)d_in[17];
    const int* src_cols = (const int*)d_in[18];
    const int* tar_rows = (const int*)d_in[19];
    const int* tar_cols = (const int*)d_in[20];
    const int* up_rows  = (const int*)d_in[21];
    const int* up_cols  = (const int*)d_in[22];
    const int* pu_rows  = (const int*)d_in[23];
    const int* pu_cols  = (const int*)d_in[24];
    const int* user_idx = (const int*)d_in[25];

    const int PD = PN * 64, UD = UN * 64;

    // ---- workspace layout (byte-identical to R5 pathA: proven to fit)
    float* F = (float*)d_ws;
    float* rowsum = F;                  // PN
    float* colsum = rowsum + PN;        // PN
    float* pos    = colsum + PN;        // PN
    u16*   ngb    = (u16*)(F + 3 * PN); // PD bf16
    u16*   nsb    = ngb + PD;           // PD bf16
    float* U0     = F + 3 * PN + PD;    // UD  (U-dim data ONLY: hg_users, users_struct)
    float* P0     = U0 + UD;            // PD pools
    float* P1     = P0 + PD;
    float* P2     = P1 + PD;
    float* P3     = P2 + PD;
    float* P4     = P3 + PD;

    int* M = (int*)(P4 + PD);           // CSR meta
    int* geo_rp = M;               int* geo_cur = geo_rp + PN + 1;
    int* tar_rp = geo_cur + PN;    int* tar_cur = tar_rp + PN + 1;
    int* src_rp = tar_cur + PN;    int* src_cur = src_rp + PN + 1;
    int* up_rp  = src_cur + PN;    int* up_cur  = up_rp + UN + 1;
    int* pu_rp  = up_cur + UN;     int* pu_cur  = pu_rp + PN + 1;
    const int meta_ints = 96006;
    int2* geo_ent = (int2*)(M + meta_ints);
    int2* tar_ent = geo_ent + NGE;
    int2* src_ent = tar_ent + NDE;
    int2* up_ent  = src_ent + NDE;
    int2* pu_ent  = up_ent + NUE;

    float* out_bu = (float*)d_out;
    float* out_fp = out_bu + (size_t)BN * 64;
    float* out_loss = out_fp + (size_t)PN * 64;

    const int RB = PN / 4;     // 2500
    const int UB = UN / 4;     // 2000
    const int NTOTB = (E4 + 255) / 256;

    // 1. zero stats + counters
    zero_kernel<<<(3 * PN + meta_ints + 255) / 256, 256, 0, stream>>>(rowsum, 3 * PN, M, meta_ints);
    // 2-4. CSR build (all 5 matrices per dispatch)
    hist_all_kernel<<<NTOTB, 256, 0, stream>>>(geo_rows, tar_rows, src_rows, up_rows, pu_rows,
                                               geo_cur, tar_cur, src_cur, up_cur, pu_cur);
    scan_all_kernel<<<5, 1024, 0, stream>>>(geo_cur, geo_rp, PN, NGE,
                                            tar_cur, tar_rp, PN, NDE,
                                            src_cur, src_rp, PN, NDE,
                                            up_cur, up_rp, UN, NUE,
                                            pu_cur, pu_rp, PN, NPUE);
    scatter_all_kernel<<<NTOTB, 256, 0, stream>>>(
        geo_rows, geo_cols, geo_vals, geo_cur, geo_ent,
        tar_rows, tar_cols, tar_vals, tar_cur, tar_ent,
        src_rows, src_cols, src_vals, src_cur, src_ent,
        up_rows, up_cols, up_vals, up_cur, up_ent,
        pu_rows, pu_cols, pu_vals, pu_cur, pu_ent);
    // 5. gates: geo_g->P0, seq_g->P1, col_g->P2 (ALL PD pools — R6 bug was col_g->U0)
    gates3_kernel<<<RB, 256, 0, stream>>>(poi, wgg, bgg, wgs, bgs, wgc, bgc, P0, P1, P2);

    SpmmJob jz = {};   // dummy
    // 6. dual: x1_g = A*geo_g + geo_g -> P3   ||   m1 = T*seq_g -> P4
    SpmmJob j_geo1 = {geo_rp, geo_ent, P0, P0, nullptr, nullptr, P3, nullptr, PN, 0};
    SpmmJob j_tar1 = {tar_rp, tar_ent, P1, nullptr, nullptr, nullptr, P4, nullptr, PN, 0};
    spmm_jobs_kernel<<<2 * RB, 256, 0, stream>>>(j_geo1, j_tar1, RB);
    // 7. geo-final: x2 = A*x1 + x1; ng = norm((geo_g+x1+x2)/3) -> P0 (aliases avg_a, elementwise-safe)
    SpmmJob j_geo2 = {geo_rp, geo_ent, P3, P3, P0, P3, P0, ngb, PN, 1};
    spmm_jobs_kernel<<<RB, 256, 0, stream>>>(j_geo2, jz, RB);
    // 8. x1_s = S*m1 + seq_g -> P3 (x1_g dead)
    SpmmJob j_s1 = {src_rp, src_ent, P4, P1, nullptr, nullptr, P3, nullptr, PN, 0};
    spmm_jobs_kernel<<<RB, 256, 0, stream>>>(j_s1, jz, RB);
    // 9. m2 = T*x1_s -> P4 (m1 dead)
    SpmmJob j_tar2 = {tar_rp, tar_ent, P3, nullptr, nullptr, nullptr, P4, nullptr, PN, 0};
    spmm_jobs_kernel<<<RB, 256, 0, stream>>>(j_tar2, jz, RB);
    // 10. ns-final: x2 = S*m2 + x1_s; ns = norm((seq_g+x1_s+x2)/3) -> P1 (aliases avg_a, safe)
    SpmmJob j_s2 = {src_rp, src_ent, P4, P3, P1, P3, P1, nsb, PN, 1};
    spmm_jobs_kernel<<<RB, 256, 0, stream>>>(j_s2, jz, RB);
    // 11. InfoNCE (MFMA); ng = P0, ns = P1
    dim3 ig(79, 79);
    infonce_mfma_kernel<<<ig, 256, 0, stream>>>(ngb, nsb, rowsum, colsum, pos);
    // 12. spmm3(up) + fuse_users -> hg_users = U0  (x0=ng, x1=ns, x2=col_g)
    spmm3_fuse_kernel<<<UB, 256, 0, stream>>>(up_rp, up_ent, P0, P1, P2, fw, fb, uemb, U0);
    // 13. hg_pois = col_g + pu*hg; fusion = norm + ng + ns -> P3 + out
    pu_out_kernel<<<RB, 256, 0, stream>>>(pu_rp, pu_ent, U0, P2, P0, P1, P3, out_fp);
    // 14. users_struct = up * fusion -> U0 (hg dead)
    SpmmJob j_upf = {up_rp, up_ent, P3, nullptr, nullptr, nullptr, U0, nullptr, UN, 0};
    spmm_jobs_kernel<<<UB, 256, 0, stream>>>(j_upf, jz, UB);
    // 15. batch_users + loss
    batch_loss_kernel<<<1025, 256, 0, stream>>>(U0, user_idx, out_bu, pos, rowsum, colsum, out_loss);
}